// Round 4
// baseline (186.826 us; speedup 1.0000x reference)
//
#include <hip/hip_runtime.h>

typedef short bf16x8 __attribute__((ext_vector_type(8)));
typedef float f32x4 __attribute__((ext_vector_type(4)));

#define MFMA16(a, b, c) __builtin_amdgcn_mfma_f32_16x16x32_bf16(a, b, c, 0, 0, 0)

constexpr int Bn = 4, Sn = 4096, En = 1024, Hn = 128;
constexpr float CSCALE = 1.44269504089f * 0.03125f;   // log2(e) * E^-0.5

// 128-row q-tiles: qt2 in [0,32), k-tiles T2 = 2*qt2+2, nch = qt2/8+1 (chunk=16 tiles)
__device__ inline int sbase(int qt2) {
    int a = qt2 >> 3, r = qt2 & 7;
    return (a + 1) * (4 * a + r);
}
constexpr int SLOT2_F = 16640;     // 128*128 O + 128 m + 128 l floats
constexpr int NIT = 320;           // 80 (qt2,ch) chunks x 4 batches

__device__ inline unsigned short f2bf(float f) {
    unsigned int u = __builtin_bit_cast(unsigned int, f);
    u += 0x7fff + ((u >> 16) & 1);
    return (unsigned short)(u >> 16);
}

__device__ inline unsigned int pk2(float a, float b) {
    unsigned int ua = __builtin_bit_cast(unsigned int, a) + 0x8000u;
    unsigned int ub = __builtin_bit_cast(unsigned int, b) + 0x8000u;
    return __builtin_amdgcn_perm(ub, ua, 0x07060302u);
}

__device__ inline void gld16(const unsigned short* g, unsigned short* l) {
    __builtin_amdgcn_global_load_lds((const __attribute__((address_space(1))) void*)g,
                                     (__attribute__((address_space(3))) void*)l, 16, 0, 0);
}

// ---------------- prep: W fp32 -> bf16, [q,k,v][h][E]; block 0 builds the
// LPT-sorted (longest-first) attn item table: 320 items (qt2, ch, b). ----------------
__global__ __launch_bounds__(256) void prep_kernel(
    const float* __restrict__ Wk, const float* __restrict__ Wq, const float* __restrict__ Wv,
    unsigned short* __restrict__ wb, unsigned int* __restrict__ sched)
{
    int gy = blockIdx.x >> 5;
    const float* src = (gy == 0) ? Wq : (gy == 1) ? Wk : Wv;
    unsigned short* dst = wb + (size_t)gy * Hn * En;
    int t = (blockIdx.x & 31) * 256 + threadIdx.x;
    const float4* s4 = (const float4*)src;
    for (int i = 0; i < 4; ++i) {
        float4 v = s4[(size_t)t * 4 + i];
        uint2 w2 = { pk2(v.x, v.y), pk2(v.z, v.w) };
        *(uint2*)&dst[(size_t)t * 16 + i * 4] = w2;
    }
    if (blockIdx.x == 0 && threadIdx.x < 80) {
        const int p = threadIdx.x;
        // p -> (qt2, ch)
        int qt2 = 0, ch = 0, acc = 0;
        for (int q = 0; q < 32; ++q) {
            int n = (q >> 3) + 1;
            if (p < acc + n) { qt2 = q; ch = p - acc; break; }
            acc += n;
        }
        int nloc = min(16, 2 * qt2 + 2 - 16 * ch);
        int key = nloc * 64 + qt2;                 // sort: nloc desc, then qt2 desc
        int rank = 0;
        for (int p2 = 0; p2 < 80; ++p2) {
            int q2 = 0, c2 = 0, a2 = 0;
            for (int q = 0; q < 32; ++q) {
                int n = (q >> 3) + 1;
                if (p2 < a2 + n) { q2 = q; c2 = p2 - a2; break; }
                a2 += n;
            }
            int nl2 = min(16, 2 * q2 + 2 - 16 * c2);
            int k2 = nl2 * 64 + q2;
            if (k2 > key || (k2 == key && p2 < p)) ++rank;
        }
        for (int b = 0; b < 4; ++b)
            sched[rank * 4 + b] = (unsigned int)(qt2 | (ch << 6) | (b << 8));
    }
}

// ---------------- QKV projection (unchanged R7 structure) ----------------
__global__ __launch_bounds__(256, 3) void proj_kernel(
    const float* __restrict__ x, const unsigned short* __restrict__ wb,
    unsigned short* __restrict__ qb, unsigned short* __restrict__ kb,
    unsigned short* __restrict__ vbT)
{
    __shared__ __align__(16) unsigned short xs[2][64][64];
    __shared__ __align__(16) unsigned short wsm[2][128][64];

    const int gy = blockIdx.y;
    const unsigned short* wg = wb + (size_t)gy * Hn * En;

    const int m0 = blockIdx.x * 64;
    const int tid = threadIdx.x;
    const int lane = tid & 63, wave = tid >> 6;
    const int l15 = lane & 15, quad = lane >> 4;
    const int wm = (wave & 1) * 32;
    const int wn = (wave >> 1) * 64;

    f32x4 acc[2][4] = {};
    float4 xp[4];

    auto loadx = [&](int kc) {
        for (int p4 = 0; p4 < 4; ++p4) {
            int i = p4 * 256 + tid, row = i >> 4, c4 = (i & 15) * 4;
            xp[p4] = *(const float4*)&x[(size_t)(m0 + row) * En + kc * 64 + c4];
        }
    };
    auto writex = [&](int c) {
        for (int p4 = 0; p4 < 4; ++p4) {
            int i = p4 * 256 + tid, row = i >> 4, hc = i & 15;
            uint2 w2 = { pk2(xp[p4].x, xp[p4].y), pk2(xp[p4].z, xp[p4].w) };
            *(uint2*)((char*)&xs[c][0][0] + row * 128 + (((hc >> 1) ^ (row & 7)) << 4) + ((hc & 1) << 3)) = w2;
        }
    };
    auto issueW = [&](int kc, int c) {
        for (int j = 0; j < 4; ++j) {
            int seg = (wave * 4 + j) * 1024;
            int d = seg + (lane << 4);
            int row = d >> 7, chp = (d >> 4) & 7;
            gld16(wg + (size_t)row * En + kc * 64 + ((chp ^ (row & 7)) << 3),
                  (unsigned short*)((char*)&wsm[c][0][0] + seg));
        }
    };

    loadx(0);
    issueW(0, 0);
    writex(0);
    loadx(1);

    for (int kc = 0; kc < En / 64; ++kc) {
        const int c = kc & 1;
        __syncthreads();
        if (kc + 1 < En / 64) {
            issueW(kc + 1, c ^ 1);
            writex(c ^ 1);
            int kn = (kc + 2 < En / 64) ? kc + 2 : En / 64 - 1;
            loadx(kn);
        }
        bf16x8 xf[2][2], wf[4][2];
        for (int i = 0; i < 2; ++i)
            for (int kk = 0; kk < 2; ++kk) {
                int row = wm + i * 16 + l15;
                int chn = (kk * 4 + quad) ^ (row & 7);
                xf[i][kk] = *(const bf16x8*)((char*)&xs[c][0][0] + row * 128 + (chn << 4));
            }
        for (int j = 0; j < 4; ++j)
            for (int kk = 0; kk < 2; ++kk) {
                int row = wn + j * 16 + l15;
                int chn = (kk * 4 + quad) ^ (row & 7);
                wf[j][kk] = *(const bf16x8*)((char*)&wsm[c][0][0] + row * 128 + (chn << 4));
            }
        if (gy != 2) {
            for (int kk = 0; kk < 2; ++kk)
                for (int i = 0; i < 2; ++i)
                    for (int j = 0; j < 4; ++j)
                        acc[i][j] = MFMA16(xf[i][kk], wf[j][kk], acc[i][j]);
        } else {
            for (int kk = 0; kk < 2; ++kk)
                for (int i = 0; i < 2; ++i)
                    for (int j = 0; j < 4; ++j)
                        acc[i][j] = MFMA16(wf[j][kk], xf[i][kk], acc[i][j]);
        }
    }

    if (gy != 2) {
        unsigned short* ob = (gy == 0) ? qb : kb;
        const float osc = (gy == 0) ? CSCALE : 1.0f;
        for (int i = 0; i < 2; ++i) {
            int rowb = m0 + wm + i * 16 + quad * 4;
            for (int j = 0; j < 4; ++j) {
                int col = wn + j * 16 + l15;
                for (int r = 0; r < 4; ++r)
                    ob[(size_t)(rowb + r) * Hn + col] = f2bf(acc[i][j][r] * osc);
            }
        }
    } else {
        for (int j = 0; j < 4; ++j) {
            int hb = wn + j * 16 + quad * 4;
            for (int i = 0; i < 2; ++i) {
                int sp = m0 + wm + i * 16 + l15;
                int bb = sp >> 12, ss = sp & 4095;
                for (int r = 0; r < 4; ++r)
                    vbT[((size_t)(bb * 128 + hb + r)) * Sn + ss] = f2bf(acc[i][j][r]);
            }
        }
    }
}

// ---------------- attention: 128-row q-tiles, 32 q-rows/wave ----------------
// Block = 4 waves x 32 q-rows = 128 q-rows; K/V LDS tile (64 keys) shared by all.
// Each wave's K-frag and V^T-frag reads are SHARED between its two 16-row q-groups
// (the LDS-BW fix: reads per unit work drop ~1.7x vs 16 q/wave).
// Grid = 320 item blocks, LPT-sorted table (longest chunks dispatched first).
__global__ __launch_bounds__(256, 2) void attn_kernel(
    const unsigned short* __restrict__ qb, const unsigned short* __restrict__ kb,
    const unsigned short* __restrict__ vbT, float* __restrict__ out,
    float* __restrict__ part, const unsigned int* __restrict__ sched)
{
    __shared__ unsigned short ks[64][132];    // K tile [key][h]
    __shared__ unsigned short vt[128][68];    // V^T [h][key]
    __shared__ unsigned short ps[4][32][72];  // per-wave P strip [q(32)][key]

    const unsigned int wi = sched[blockIdx.x];
    const int qt2 = (int)(wi & 63u);
    const int ch  = (int)((wi >> 6) & 3u);
    const int b   = (int)((wi >> 8) & 3u);
    const int T2  = 2 * qt2 + 2;              // total k-tiles for this q-tile
    const int nch = (qt2 >> 3) + 1;
    const int t0 = ch * 16;
    const int nloc = min(16, T2 - t0);
    const int q0 = qt2 * 128;

    const int tid = threadIdx.x;
    const int lane = tid & 63, wave = tid >> 6;
    const int l15 = lane & 15, quad = lane >> 4;

    const unsigned short* qg = qb + (size_t)(b * Sn + q0) * Hn;
    bf16x8 qf[2][4];
    for (int g = 0; g < 2; ++g)
        for (int f = 0; f < 4; ++f)
            qf[g][f] = *(const bf16x8*)&qg[(wave * 32 + g * 16 + l15) * Hn + f * 32 + quad * 8];

    f32x4 o[2][8] = {};          // O^T per group: h = t*16+quad*4+r, q = l15
    float m_r[2] = { -INFINITY, -INFINITY }, l_r[2] = { 0.f, 0.f };

    const unsigned short* kg = kb + (size_t)b * Sn * Hn;
    const unsigned short* vg = vbT + (size_t)b * 128 * Sn;

    bf16x8 kreg[4], vreg[4];
    auto loadKV = [&](int gt) {
        int kt0 = gt * 64;
        for (int p4 = 0; p4 < 4; ++p4) {
            int i = p4 * 256 + tid;
            kreg[p4] = *(const bf16x8*)&kg[(size_t)(kt0 + (i >> 4)) * Hn + (i & 15) * 8];
            vreg[p4] = *(const bf16x8*)&vg[(size_t)(i >> 3) * Sn + kt0 + (i & 7) * 8];
        }
    };

    loadKV(t0);
    for (int tl = 0; tl < nloc; ++tl) {
        const int gt = t0 + tl;
        for (int p4 = 0; p4 < 4; ++p4) {
            int i = p4 * 256 + tid;
            *(bf16x8*)&ks[i >> 4][(i & 15) * 8] = kreg[p4];
            *(bf16x8*)&vt[i >> 3][(i & 7) * 8] = vreg[p4];
        }
        __syncthreads();
        if (tl + 1 < nloc) loadKV(gt + 1);

        // S^T: A = K (m=key), B = Q group g. kf read once, used by BOTH groups.
        float u[2][4][4];
        for (int nt = 0; nt < 4; ++nt) {
            f32x4 s0 = {}, s1 = {};
            for (int kk = 0; kk < 4; ++kk) {
                bf16x8 kf = *(const bf16x8*)&ks[nt * 16 + l15][kk * 32 + quad * 8];
                s0 = MFMA16(kf, qf[0][kk], s0);
                s1 = MFMA16(kf, qf[1][kk], s1);
            }
            for (int r = 0; r < 4; ++r) { u[0][nt][r] = s0[r]; u[1][nt][r] = s1[r]; }
        }
        if (gt >= 2 * qt2) {      // diagonal tiles: mask keys > q
            int kof = (gt - 2 * qt2) * 64;
            for (int g = 0; g < 2; ++g) {
                int qq = wave * 32 + g * 16 + l15;
                for (int nt = 0; nt < 4; ++nt)
                    for (int r = 0; r < 4; ++r)
                        if (kof + nt * 16 + quad * 4 + r > qq) u[g][nt][r] = -INFINITY;
            }
        }
        // per-lane online softmax, per q-group (log2 domain; CSCALE folded into q)
        for (int g = 0; g < 2; ++g) {
            float mx = -INFINITY;
            for (int nt = 0; nt < 4; ++nt)
                for (int r = 0; r < 4; ++r) mx = fmaxf(mx, u[g][nt][r]);
            mx = fmaxf(mx, __shfl_xor(mx, 16));
            mx = fmaxf(mx, __shfl_xor(mx, 32));
            float mn = fmaxf(m_r[g], mx);
            float alpha = exp2f(m_r[g] - mn);
            m_r[g] = mn;
            float sum = 0.f;
            for (int nt = 0; nt < 4; ++nt)
                for (int r = 0; r < 4; ++r) {
                    float pv = exp2f(u[g][nt][r] - mn);
                    u[g][nt][r] = pv;
                    sum += pv;
                }
            sum += __shfl_xor(sum, 16);
            sum += __shfl_xor(sum, 32);
            l_r[g] = l_r[g] * alpha + sum;

            unsigned short* psrow = &ps[wave][g * 16 + l15][0];
            for (int nt = 0; nt < 4; ++nt) {
                uint2 w2 = { pk2(u[g][nt][0], u[g][nt][1]), pk2(u[g][nt][2], u[g][nt][3]) };
                *(uint2*)&psrow[nt * 16 + quad * 4] = w2;
            }
            for (int t = 0; t < 8; ++t) o[g][t] *= alpha;
        }

        // O^T += V^T P^T — vf read once, used by BOTH groups.
        for (int k2 = 0; k2 < 2; ++k2) {
            bf16x8 pf0 = *(const bf16x8*)&ps[wave][0 * 16 + l15][k2 * 32 + quad * 8];
            bf16x8 pf1 = *(const bf16x8*)&ps[wave][1 * 16 + l15][k2 * 32 + quad * 8];
            for (int t = 0; t < 8; ++t) {
                bf16x8 vf = *(const bf16x8*)&vt[t * 16 + l15][k2 * 32 + quad * 8];
                o[0][t] = MFMA16(vf, pf0, o[0][t]);
                o[1][t] = MFMA16(vf, pf1, o[1][t]);
            }
        }
        __syncthreads();   // protect ks/vt before next iteration's writes
    }

    if (nch == 1) {
        for (int g = 0; g < 2; ++g) {
            float inv = 1.0f / l_r[g];
            float* og = out + (size_t)(b * Sn + q0 + wave * 32 + g * 16 + l15) * Hn;
            for (int t = 0; t < 8; ++t) {
                float4 st = { o[g][t][0] * inv, o[g][t][1] * inv, o[g][t][2] * inv, o[g][t][3] * inv };
                *(float4*)&og[t * 16 + quad * 4] = st;
            }
        }
    } else {
        float* P = part + (size_t)(b * 80 + sbase(qt2) + ch) * SLOT2_F;
        for (int g = 0; g < 2; ++g) {
            int q = wave * 32 + g * 16 + l15;
            for (int t = 0; t < 8; ++t) {
                float4 st = { o[g][t][0], o[g][t][1], o[g][t][2], o[g][t][3] };
                *(float4*)&P[q * 128 + t * 16 + quad * 4] = st;
            }
            if (quad == 0) {
                P[16384 + q] = m_r[g];
                P[16512 + q] = l_r[g];
            }
        }
    }
}

// ---------------- merge partials for qt2 >= 8 ----------------
// grid (48, B): qt2 = 8 + bx/2, half = bx&1; 256 thr: q = half*64 + tid>>2, h0 = (tid&3)*32
__global__ __launch_bounds__(256) void merge_kernel(
    const float* __restrict__ part, float* __restrict__ out)
{
    const int qt2 = 8 + (blockIdx.x >> 1);
    const int half = blockIdx.x & 1;
    const int b = blockIdx.y;
    const int nch = (qt2 >> 3) + 1;
    const float* P0 = part + (size_t)(b * 80 + sbase(qt2)) * SLOT2_F;
    const int q = half * 64 + (threadIdx.x >> 2);
    const int h0 = (threadIdx.x & 3) * 32;

    float m[4], w[4];
    float M = -INFINITY;
    for (int c = 0; c < nch; ++c) {
        m[c] = P0[(size_t)c * SLOT2_F + 16384 + q];
        M = fmaxf(M, m[c]);
    }
    float L = 0.f;
    for (int c = 0; c < nch; ++c) {
        w[c] = exp2f(m[c] - M);
        L += w[c] * P0[(size_t)c * SLOT2_F + 16512 + q];
    }
    float inv = 1.0f / L;

    float acc[32] = {};
    for (int c = 0; c < nch; ++c) {
        const float* Pq = P0 + (size_t)c * SLOT2_F + q * 128 + h0;
        for (int j = 0; j < 8; ++j) {
            float4 v = *(const float4*)&Pq[j * 4];
            acc[j * 4 + 0] += w[c] * v.x;
            acc[j * 4 + 1] += w[c] * v.y;
            acc[j * 4 + 2] += w[c] * v.z;
            acc[j * 4 + 3] += w[c] * v.w;
        }
    }
    float* og = out + (size_t)(b * Sn + qt2 * 128 + q) * Hn + h0;
    for (int j = 0; j < 8; ++j) {
        float4 st = { acc[j * 4 + 0] * inv, acc[j * 4 + 1] * inv,
                      acc[j * 4 + 2] * inv, acc[j * 4 + 3] * inv };
        *(float4*)&og[j * 4] = st;
    }
}

extern "C" void kernel_launch(void* const* d_in, const int* in_sizes, int n_in,
                              void* d_out, int out_size, void* d_ws, size_t ws_size,
                              hipStream_t stream)
{
    const float* x  = (const float*)d_in[0];
    const float* Wk = (const float*)d_in[1];
    const float* Wq = (const float*)d_in[2];
    const float* Wv = (const float*)d_in[3];
    float* out = (float*)d_out;

    unsigned short* qbuf  = (unsigned short*)d_ws;                  // 4 MB (pre-scaled)
    unsigned short* kbuf  = qbuf + (size_t)Bn * Sn * Hn;            // 4 MB
    unsigned short* vbufT = kbuf + (size_t)Bn * Sn * Hn;            // 4 MB, [b][h][s]
    unsigned short* wb    = vbufT + (size_t)Bn * Sn * Hn;           // 0.75 MB bf16 W
    float* part = (float*)(wb + (size_t)3 * Hn * En);               // 21.3 MB partials
    // schedule table in part[0..320) uints; earliest partial write is slot 8
    // (float offset 8*SLOT2_F = 133120) — no overlap
    unsigned int* sched = (unsigned int*)part;

    prep_kernel<<<96, 256, 0, stream>>>(Wk, Wq, Wv, wb, sched);
    proj_kernel<<<dim3(Bn * Sn / 64, 3), 256, 0, stream>>>(x, wb, qbuf, kbuf, vbufT);
    attn_kernel<<<NIT, 256, 0, stream>>>(qbuf, kbuf, vbufT, out, part, sched);
    merge_kernel<<<dim3(48, Bn), 256, 0, stream>>>(part, out);
}

// Round 5
// 176.360 us; speedup vs baseline: 1.0593x; 1.0593x over previous
//
#include <hip/hip_runtime.h>

typedef short bf16x8 __attribute__((ext_vector_type(8)));
typedef float f32x4 __attribute__((ext_vector_type(4)));

#define MFMA16(a, b, c) __builtin_amdgcn_mfma_f32_16x16x32_bf16(a, b, c, 0, 0, 0)

constexpr int Bn = 4, Sn = 4096, En = 1024, Hn = 128;
constexpr float CSCALE = 1.44269504089f * 0.03125f;   // log2(e) * E^-0.5

// attn partials: qt64 uses ceil((qt64+1)/16) chunks; slot base = prefix sum
__device__ inline int sb64(int qt) {
    int a = qt >> 4, r = qt & 15;
    return 8 * a * (a + 1) + r * (a + 1);
}
constexpr int SB = 160;            // sb64(64)
constexpr int SLOT_F = 8320;       // 64*128 O + 64 m + 64 l floats

__device__ inline unsigned short f2bf(float f) {
    unsigned int u = __builtin_bit_cast(unsigned int, f);
    u += 0x7fff + ((u >> 16) & 1);
    return (unsigned short)(u >> 16);
}

__device__ inline unsigned int pk2(float a, float b) {
    unsigned int ua = __builtin_bit_cast(unsigned int, a) + 0x8000u;
    unsigned int ub = __builtin_bit_cast(unsigned int, b) + 0x8000u;
    return __builtin_amdgcn_perm(ub, ua, 0x07060302u);
}

__device__ inline void gld16(const unsigned short* g, unsigned short* l) {
    __builtin_amdgcn_global_load_lds((const __attribute__((address_space(1))) void*)g,
                                     (__attribute__((address_space(3))) void*)l, 16, 0, 0);
}

// ---------------- prep: W fp32 -> bf16, [q,k,v][h][E] = rows 0..383; block 0 builds
// the static balanced attn schedule (R3 version, verified 48.7 us) ----------------
__global__ __launch_bounds__(256) void prep_kernel(
    const float* __restrict__ Wk, const float* __restrict__ Wq, const float* __restrict__ Wv,
    unsigned short* __restrict__ wb, unsigned int* __restrict__ sched)
{
    int gy = blockIdx.x >> 5;
    const float* src = (gy == 0) ? Wq : (gy == 1) ? Wk : Wv;
    unsigned short* dst = wb + (size_t)gy * Hn * En;
    int t = (blockIdx.x & 31) * 256 + threadIdx.x;
    const float4* s4 = (const float4*)src;
    for (int i = 0; i < 4; ++i) {
        float4 v = s4[(size_t)t * 4 + i];
        uint2 w2 = { pk2(v.x, v.y), pk2(v.z, v.w) };
        *(uint2*)&dst[(size_t)t * 16 + i * 4] = w2;
    }
    if (blockIdx.x == 0) {
        const int bin = threadIdx.x;
        unsigned int it[4] = { 0xFFFFu, 0xFFFFu, 0xFFFFu, 0xFFFFu };
        auto fullItem = [](int k) -> unsigned int {
            int b = k / 100, j = k - 100 * b;
            int qt = 63, ch = 0;
            for (int q = 63; q >= 0; --q) {
                int f = (q + 1) >> 4;
                if (j < f) { qt = q; ch = j; break; }
                j -= f;
            }
            return (unsigned int)(qt | (ch << 6) | (b << 8));
        };
        auto remItem = [](int v, int i) -> unsigned int {
            int rep = i >> 2, b = i & 3;
            int qt = rep * 16 + v - 1, ch = rep;
            return (unsigned int)(qt | (ch << 6) | (b << 8));
        };
        if (bin < 128) {
            it[0] = fullItem(2 * bin);
            it[1] = fullItem(2 * bin + 1);
        } else if (bin < 240) {
            int t2 = bin - 128, v = 2 + (t2 >> 4), i = t2 & 15;
            it[0] = fullItem(256 + t2);
            it[1] = remItem(v, i);
            it[2] = remItem(17 - v, i);
        } else {
            int t2 = bin - 240;
            it[0] = fullItem(368 + 2 * t2);
            it[1] = fullItem(369 + 2 * t2);
            it[2] = remItem(1, t2);
        }
        for (int z = 0; z < 4; ++z) sched[z * 256 + bin] = it[z];
    }
}

// ---------------- fused QKV projection: ONE pass over x, all 3 outputs ----------------
// grid 256 x 512 thr (8 waves). Block = 64 x-rows times all 384 W-rows (q|k|v).
// Wave w: all 64 rows (4 m-tiles) x 48 cols (3 n-tiles) at wn = w*48.
// x staged once per k-chunk (fp32->bf16, swizzled); W staged via gld16 (bf16, dbuf).
// Cuts x HBM traffic 3x vs the per-gy version (192 MB -> 64 MB).
__global__ __launch_bounds__(512, 2) void proj_kernel(
    const float* __restrict__ x, const unsigned short* __restrict__ wb,
    unsigned short* __restrict__ qb, unsigned short* __restrict__ kb,
    unsigned short* __restrict__ vbT)
{
    __shared__ __align__(16) unsigned short xs[2][64][64];     // 2 x 8 KB
    __shared__ __align__(16) unsigned short wsm[2][384][64];   // 2 x 48 KB

    const int m0 = blockIdx.x * 64;
    const int tid = threadIdx.x;
    const int lane = tid & 63, wave = tid >> 6;
    const int l15 = lane & 15, quad = lane >> 4;
    const int wn = wave * 48;

    f32x4 acc[4][3] = {};
    float4 xp[2];

    auto loadx = [&](int kc) {
        for (int p2 = 0; p2 < 2; ++p2) {
            int i = p2 * 512 + tid, row = i >> 4, c4 = (i & 15) * 4;
            xp[p2] = *(const float4*)&x[(size_t)(m0 + row) * En + kc * 64 + c4];
        }
    };
    auto writex = [&](int c) {
        for (int p2 = 0; p2 < 2; ++p2) {
            int i = p2 * 512 + tid, row = i >> 4, hc = i & 15;
            uint2 w2 = { pk2(xp[p2].x, xp[p2].y), pk2(xp[p2].z, xp[p2].w) };
            *(uint2*)((char*)&xs[c][0][0] + row * 128 + (((hc >> 1) ^ (row & 7)) << 4) + ((hc & 1) << 3)) = w2;
        }
    };
    auto issueW = [&](int kc, int c) {
        for (int j = 0; j < 6; ++j) {
            int seg = (wave * 6 + j) * 1024;
            int d = seg + (lane << 4);
            int row = d >> 7, chp = (d >> 4) & 7;
            gld16(wb + (size_t)row * En + kc * 64 + ((chp ^ (row & 7)) << 3),
                  (unsigned short*)((char*)&wsm[c][0][0] + seg));
        }
    };

    loadx(0);
    issueW(0, 0);
    writex(0);
    loadx(1);

    for (int kc = 0; kc < En / 64; ++kc) {
        const int c = kc & 1;
        __syncthreads();
        if (kc + 1 < En / 64) {
            issueW(kc + 1, c ^ 1);
            writex(c ^ 1);
            int kn = (kc + 2 < En / 64) ? kc + 2 : En / 64 - 1;
            loadx(kn);
        }
        bf16x8 xf[4][2], wf[3][2];
        for (int i = 0; i < 4; ++i)
            for (int kk = 0; kk < 2; ++kk) {
                int row = i * 16 + l15;
                int chn = (kk * 4 + quad) ^ (row & 7);
                xf[i][kk] = *(const bf16x8*)((char*)&xs[c][0][0] + row * 128 + (chn << 4));
            }
        for (int j = 0; j < 3; ++j)
            for (int kk = 0; kk < 2; ++kk) {
                int row = wn + j * 16 + l15;
                int chn = (kk * 4 + quad) ^ (row & 7);
                wf[j][kk] = *(const bf16x8*)((char*)&wsm[c][0][0] + row * 128 + (chn << 4));
            }
        for (int kk = 0; kk < 2; ++kk)
            for (int i = 0; i < 4; ++i)
                for (int j = 0; j < 3; ++j)
                    acc[i][j] = MFMA16(xf[i][kk], wf[j][kk], acc[i][j]);
    }

    // epilogue: gy = global col / 128 (wave-uniform per j-tile)
    for (int i = 0; i < 4; ++i) {
        int rowb = m0 + i * 16 + quad * 4;
        for (int j = 0; j < 3; ++j) {
            int gcol = wn + j * 16 + l15;
            int gy = gcol >> 7, col = gcol & 127;
            if (gy == 0) {
                for (int r = 0; r < 4; ++r)
                    qb[(size_t)(rowb + r) * Hn + col] = f2bf(acc[i][j][r] * CSCALE);
            } else if (gy == 1) {
                for (int r = 0; r < 4; ++r)
                    kb[(size_t)(rowb + r) * Hn + col] = f2bf(acc[i][j][r]);
            } else {
                int bb = rowb >> 12, ss = rowb & 4095;
                uint2 w2 = { pk2(acc[i][j][0], acc[i][j][1]), pk2(acc[i][j][2], acc[i][j][3]) };
                *(uint2*)&vbT[((size_t)(bb * 128 + col)) * Sn + ss] = w2;
            }
        }
    }
}

// ---------------- attention: static balanced schedule (R3, verified 48.7 us) --------
__global__ __launch_bounds__(256, 3) void attn_kernel(
    const unsigned short* __restrict__ qb, const unsigned short* __restrict__ kb,
    const unsigned short* __restrict__ vbT, float* __restrict__ out,
    float* __restrict__ part, const unsigned int* __restrict__ sched)
{
    __shared__ unsigned short ks[64][132];    // K tile [key][h]
    __shared__ unsigned short vt[128][68];    // V^T [h][key]
    __shared__ unsigned short ps[4][16][72];  // per-wave P strip [q][key]

    const unsigned int wi = sched[blockIdx.x];
    if (wi == 0xFFFFu) return;
    const int qt = (int)(wi & 63u);
    const int ch = (int)((wi >> 6) & 3u);
    const int b  = (int)((wi >> 8) & 3u);
    const int T  = qt + 1;                    // total k-tiles for this q-tile
    const int nch = (T + 15) >> 4;
    const int t0 = ch * 16;
    const int nloc = min(16, T - t0);
    const int q0 = qt * 64;

    const int tid = threadIdx.x;
    const int lane = tid & 63, wave = tid >> 6;
    const int l15 = lane & 15, quad = lane >> 4;

    const unsigned short* qg = qb + (size_t)(b * Sn + q0) * Hn;
    bf16x8 qf[4];
    for (int f = 0; f < 4; ++f)
        qf[f] = *(const bf16x8*)&qg[(wave * 16 + l15) * Hn + f * 32 + quad * 8];

    f32x4 o[8] = {};             // O^T: h = t*16+quad*4+r, q = l15 (this wave's row group)
    float m_r = -INFINITY, l_r = 0.f;

    const unsigned short* kg = kb + (size_t)b * Sn * Hn;
    const unsigned short* vg = vbT + (size_t)b * 128 * Sn;
    unsigned short* psrow = &ps[wave][l15][0];

    bf16x8 kreg[4], vreg[4];
    auto loadKV = [&](int gt) {
        int kt0 = gt * 64;
        for (int p4 = 0; p4 < 4; ++p4) {
            int i = p4 * 256 + tid;
            kreg[p4] = *(const bf16x8*)&kg[(size_t)(kt0 + (i >> 4)) * Hn + (i & 15) * 8];
            vreg[p4] = *(const bf16x8*)&vg[(size_t)(i >> 3) * Sn + kt0 + (i & 7) * 8];
        }
    };

    loadKV(t0);
    for (int tl = 0; tl < nloc; ++tl) {
        const int gt = t0 + tl;
        for (int p4 = 0; p4 < 4; ++p4) {
            int i = p4 * 256 + tid;
            *(bf16x8*)&ks[i >> 4][(i & 15) * 8] = kreg[p4];
            *(bf16x8*)&vt[i >> 3][(i & 7) * 8] = vreg[p4];
        }
        __syncthreads();
        if (tl + 1 < nloc) loadKV(gt + 1);

        // S^T: A = K (m=key), B = Q (n=q). u[nt][r]: key = gt*64+nt*16+quad*4+r, q = l15
        float u[4][4];
        for (int nt = 0; nt < 4; ++nt) {
            f32x4 s = {};
            for (int kk = 0; kk < 4; ++kk) {
                bf16x8 kf = *(const bf16x8*)&ks[nt * 16 + l15][kk * 32 + quad * 8];
                s = MFMA16(kf, qf[kk], s);
            }
            for (int r = 0; r < 4; ++r) u[nt][r] = s[r];
        }
        if (gt == qt) {   // only the last tile intersects the diagonal
            int qq = wave * 16 + l15;
            for (int nt = 0; nt < 4; ++nt)
                for (int r = 0; r < 4; ++r)
                    if (nt * 16 + quad * 4 + r > qq) u[nt][r] = -INFINITY;
        }
        // per-lane online softmax (log2 domain; CSCALE folded into q at projection)
        float mx = -INFINITY;
        for (int nt = 0; nt < 4; ++nt)
            for (int r = 0; r < 4; ++r) mx = fmaxf(mx, u[nt][r]);
        mx = fmaxf(mx, __shfl_xor(mx, 16));
        mx = fmaxf(mx, __shfl_xor(mx, 32));
        float mn = fmaxf(m_r, mx);
        float alpha = exp2f(m_r - mn);
        m_r = mn;
        float sum = 0.f;
        for (int nt = 0; nt < 4; ++nt)
            for (int r = 0; r < 4; ++r) {
                float pv = exp2f(u[nt][r] - mn);
                u[nt][r] = pv;
                sum += pv;
            }
        sum += __shfl_xor(sum, 16);
        sum += __shfl_xor(sum, 32);
        l_r = l_r * alpha + sum;

        // P -> LDS [q][key] (same-wave strip; no barrier needed)
        for (int nt = 0; nt < 4; ++nt) {
            uint2 w2 = { pk2(u[nt][0], u[nt][1]), pk2(u[nt][2], u[nt][3]) };
            *(uint2*)&psrow[nt * 16 + quad * 4] = w2;
        }
        for (int t = 0; t < 8; ++t) o[t] *= alpha;

        // O^T += V^T P^T
        for (int k2 = 0; k2 < 2; ++k2) {
            bf16x8 pf = *(const bf16x8*)&psrow[k2 * 32 + quad * 8];
            for (int t = 0; t < 8; ++t) {
                bf16x8 vf = *(const bf16x8*)&vt[t * 16 + l15][k2 * 32 + quad * 8];
                o[t] = MFMA16(vf, pf, o[t]);
            }
        }
        __syncthreads();   // protect ks/vt before next iteration's writes
    }

    if (nch == 1) {
        float inv = 1.0f / l_r;
        float* og = out + (size_t)(b * Sn + q0 + wave * 16 + l15) * Hn;
        for (int t = 0; t < 8; ++t) {
            float4 st = { o[t][0] * inv, o[t][1] * inv, o[t][2] * inv, o[t][3] * inv };
            *(float4*)&og[t * 16 + quad * 4] = st;
        }
    } else {
        float* P = part + (size_t)(b * SB + sb64(qt) + ch) * SLOT_F;
        int q = wave * 16 + l15;
        for (int t = 0; t < 8; ++t) {
            float4 st = { o[t][0], o[t][1], o[t][2], o[t][3] };
            *(float4*)&P[q * 128 + t * 16 + quad * 4] = st;
        }
        if (quad == 0) {
            P[8192 + q] = m_r;
            P[8256 + q] = l_r;
        }
    }
}

// ---------------- merge partials for qt >= 16 ----------------
// grid (48, B), 256 thr: q = tid>>2 (64 rows), h0 = (tid&3)*32 (32 h each)
__global__ __launch_bounds__(256) void merge_kernel(
    const float* __restrict__ part, float* __restrict__ out)
{
    const int qt = 16 + blockIdx.x;
    const int b = blockIdx.y;
    const int nch = (qt + 16) >> 4;
    const float* P0 = part + (size_t)(b * SB + sb64(qt)) * SLOT_F;
    const int q = threadIdx.x >> 2;
    const int h0 = (threadIdx.x & 3) * 32;

    float m[4], w[4];
    float M = -INFINITY;
    for (int c = 0; c < nch; ++c) {
        m[c] = P0[(size_t)c * SLOT_F + 8192 + q];
        M = fmaxf(M, m[c]);
    }
    float L = 0.f;
    for (int c = 0; c < nch; ++c) {
        w[c] = exp2f(m[c] - M);
        L += w[c] * P0[(size_t)c * SLOT_F + 8256 + q];
    }
    float inv = 1.0f / L;

    float acc[32] = {};
    for (int c = 0; c < nch; ++c) {
        const float* Pq = P0 + (size_t)c * SLOT_F + q * 128 + h0;
        for (int j = 0; j < 8; ++j) {
            float4 v = *(const float4*)&Pq[j * 4];
            acc[j * 4 + 0] += w[c] * v.x;
            acc[j * 4 + 1] += w[c] * v.y;
            acc[j * 4 + 2] += w[c] * v.z;
            acc[j * 4 + 3] += w[c] * v.w;
        }
    }
    float* og = out + (size_t)(b * Sn + qt * 64 + q) * Hn + h0;
    for (int j = 0; j < 8; ++j) {
        float4 st = { acc[j * 4 + 0] * inv, acc[j * 4 + 1] * inv,
                      acc[j * 4 + 2] * inv, acc[j * 4 + 3] * inv };
        *(float4*)&og[j * 4] = st;
    }
}

extern "C" void kernel_launch(void* const* d_in, const int* in_sizes, int n_in,
                              void* d_out, int out_size, void* d_ws, size_t ws_size,
                              hipStream_t stream)
{
    const float* x  = (const float*)d_in[0];
    const float* Wk = (const float*)d_in[1];
    const float* Wq = (const float*)d_in[2];
    const float* Wv = (const float*)d_in[3];
    float* out = (float*)d_out;

    unsigned short* qbuf  = (unsigned short*)d_ws;                  // 4 MB (pre-scaled)
    unsigned short* kbuf  = qbuf + (size_t)Bn * Sn * Hn;            // 4 MB
    unsigned short* vbufT = kbuf + (size_t)Bn * Sn * Hn;            // 4 MB, [b][h][s]
    unsigned short* wb    = vbufT + (size_t)Bn * Sn * Hn;           // 0.75 MB bf16 W
    float* part = (float*)(wb + (size_t)3 * Hn * En);               // 21.3 MB partials
    // schedule table lives in part[0..1024) uints; earliest partial write is
    // float offset 16*SLOT_F = 133120 — no overlap
    unsigned int* sched = (unsigned int*)part;

    prep_kernel<<<96, 256, 0, stream>>>(Wk, Wq, Wv, wb, sched);
    proj_kernel<<<256, 512, 0, stream>>>(x, wb, qbuf, kbuf, vbufT);
    attn_kernel<<<1024, 256, 0, stream>>>(qbuf, kbuf, vbufT, out, part, sched);
    merge_kernel<<<dim3(48, Bn), 256, 0, stream>>>(part, out);
}